// Round 7
// baseline (60.234 us; speedup 1.0000x reference)
//
#include <hip/hip_runtime.h>
#include <cstdint>
#include <cstddef>

// ---------------------------------------------------------------------------
// DeepIM: VAE (matvec chain) + 2-layer GAT on 1%-dense adjacency.
//  - GAT heads are rank-1 => logits e[i,j]=leaky(c1*xh[i]+c2*xh[j]); head
//    outputs collapse to scalars. No NxN / Nx64 intermediates.
//  - adjacency (int32/float32 words; R1 counters ruled out packed bytes)
//    -> 2MB bitmap (permuted mapping), ctz-scanned by both GAT layers.
//  - R7 structure: 8 dispatches; the 67MB adjacency->bitmap conversion is
//    TAPER-PACKED across six dispatches (conv blocks FIRST in each grid) so
//    every node runs near HBM BW. Stream order guarantees bitmap complete
//    before gat_heads.
//  - R3/R4 lesson: device-scope spin barriers cost ~70us each at 512 blocks —
//    never hand-roll grid sync; dispatch boundaries are ~1.2us.
//  - R5/R6 lesson: side-work must be wide (>=~100 blocks), placed at LOW
//    blockIdx (long pole starts first), and not gated on a dependent load.
// ---------------------------------------------------------------------------

typedef unsigned long long u64;

#define ACT_RELU 1
#define ACT_SIG  2

__device__ __forceinline__ float d4(float4 a, float4 b) {
  return a.x * b.x + a.y * b.y + a.z * b.z + a.w * b.w;
}
__device__ __forceinline__ float waveRed(float v) {
  for (int o = 32; o; o >>= 1) v += __shfl_down(v, o);
  return v;  // lane 0 holds sum
}

// conv: one adjacency row (4096 int32 words) -> 64 bitmap words, permuted:
//   bm word q (=it*4+c), bit b  <->  column (q>>2)*256 + 4*b + (q&3)
__device__ __forceinline__ void convRow(const uint4* aw, u64* bm, int r, int lane) {
  const uint4* rp = aw + (size_t)r * 1024u;
#pragma unroll
  for (int it = 0; it < 16; ++it) {
    const uint4 v = rp[it * 64 + lane];
    const u64 m0 = __ballot(v.x != 0u);
    const u64 m1 = __ballot(v.y != 0u);
    const u64 m2 = __ballot(v.z != 0u);
    const u64 m3 = __ballot(v.w != 0u);
    if (lane < 4) {
      const u64 mv = lane == 0 ? m0 : lane == 1 ? m1 : lane == 2 ? m2 : m3;
      bm[(size_t)r * 64 + it * 4 + lane] = mv;
    }
  }
}

// Conv side-work at LOW blockIdx: blocks [0,CB) convert rows
// [convBase, convBase+CB*4). Returns true if this block was a conv block.
__device__ __forceinline__ bool convFirst(int CB, int convBase, const void* adj,
                                          u64* bm) {
  if ((int)blockIdx.x >= CB) return false;
  const int row = convBase + blockIdx.x * 4 + (threadIdx.x >> 6);
  convRow((const uint4*)adj, bm, row, threadIdx.x & 63);
  return true;
}

// Mega dispatch #1: [0,448) conv rows [0,1792); [448,1472) enc1; 1472 prep.
struct MegaP {
  const void* adj;
  u64* bm;
  const float *w1, *x, *b1;
  float* h1;
  const float *gw, *ga, *ow, *oa;
  float* consts;  // [c1(4), c2(4), d(4), oa0, oa1]
};

__global__ __launch_bounds__(256) void mega_kernel(MegaP p) {
  const int tid = threadIdx.x, w = tid >> 6, lane = tid & 63;
  const int blk = blockIdx.x;
  if (blk < 448) {                         // ---- conv rows [0,1792)
    convRow((const uint4*)p.adj, p.bm, blk * 4 + w, lane);
    return;
  }
  if (blk < 1472) {                        // ---- enc1 row
    const int r = blk - 448;
    const float4* row = (const float4*)(p.w1 + (size_t)r * 4096u);
    const float4* x4 = (const float4*)p.x;
    float acc = 0.f;
#pragma unroll
    for (int k = 0; k < 4; ++k) {
      const int idx = tid + 256 * k;
      acc += d4(row[idx], x4[idx]);
    }
    acc = waveRed(acc);
    __shared__ float lds[4];
    if (lane == 0) lds[w] = acc;
    __syncthreads();
    if (tid == 0) {
      const float v = lds[0] + lds[1] + lds[2] + lds[3] + p.b1[r];
      p.h1[r] = v > 0.f ? v : 0.f;
    }
    return;
  }
  // ---- prep: per-head scalars (1 block)
  const int h = w, k = lane;
  const float wv = p.gw[h * 64 + k];
  float p1 = wv * p.ga[h * 128 + k];
  float p2 = wv * p.ga[h * 128 + 64 + k];
  float p3 = wv * p.ow[h * 64 + k];
  for (int off = 32; off; off >>= 1) {
    p1 += __shfl_down(p1, off);
    p2 += __shfl_down(p2, off);
    p3 += __shfl_down(p3, off);
  }
  if (k == 0) { p.consts[h] = p1; p.consts[4 + h] = p2; p.consts[8 + h] = p3; }
  if (tid == 0) { p.consts[12] = p.oa[0]; p.consts[13] = p.oa[1]; }
}

// y[r]=act(dot(W[r,:],x)+b[r]); blocks [0,CB)=conv, [CB,CB+R)=matvec rows.
template<int ACT>
__global__ __launch_bounds__(256) void mv_conv_kernel(const float* __restrict__ W,
    const float* __restrict__ x, const float* __restrict__ b,
    float* __restrict__ y, int C, int CB, int convBase,
    const void* __restrict__ adj, u64* __restrict__ bm) {
  if (convFirst(CB, convBase, adj, bm)) return;
  const int r = blockIdx.x - CB;
  const float* row = W + (size_t)r * (size_t)C;
  float acc = 0.f;
  for (int c = threadIdx.x * 4; c < C; c += 256 * 4) {
    const float4 w4 = *reinterpret_cast<const float4*>(row + c);
    const float4 x4 = *reinterpret_cast<const float4*>(x + c);
    acc += d4(w4, x4);
  }
  acc = waveRed(acc);
  __shared__ float lds[4];
  if ((threadIdx.x & 63) == 0) lds[threadIdx.x >> 6] = acc;
  __syncthreads();
  if (threadIdx.x == 0) {
    float v = lds[0] + lds[1] + lds[2] + lds[3] + b[r];
    if (ACT == ACT_RELU) v = v > 0.f ? v : 0.f;
    if (ACT == ACT_SIG)  v = 1.f / (1.f + expf(-v));
    y[r] = v;
  }
}

// mu (rows 0..511 via w3) / logvar (rows 512..1023 via w4) + conv side-work.
__global__ __launch_bounds__(256) void mulv_conv_kernel(const float* __restrict__ w3,
    const float* __restrict__ b3, const float* __restrict__ w4,
    const float* __restrict__ b4, const float* __restrict__ h2,
    float* __restrict__ mu, float* __restrict__ logvar, int CB, int convBase,
    const void* __restrict__ adj, u64* __restrict__ bm) {
  if (convFirst(CB, convBase, adj, bm)) return;
  const int r = blockIdx.x - CB;
  const bool is_mu = r < 512;
  const int rr = is_mu ? r : r - 512;
  const float* row = (is_mu ? w3 : w4) + (size_t)rr * 1024u;
  const int c = threadIdx.x * 4;
  float acc = d4(*reinterpret_cast<const float4*>(row + c),
                 *reinterpret_cast<const float4*>(h2 + c));
  acc = waveRed(acc);
  __shared__ float lds[4];
  if ((threadIdx.x & 63) == 0) lds[threadIdx.x >> 6] = acc;
  __syncthreads();
  if (threadIdx.x == 0) {
    const float v = lds[0] + lds[1] + lds[2] + lds[3] + (is_mu ? b3[rr] : b4[rr]);
    (is_mu ? mu : logvar)[rr] = v;
  }
}

// dec1 with z = mu + eps*exp(0.5*logvar) computed in LDS + conv side-work.
__global__ __launch_bounds__(256) void dec1_conv_kernel(const float* __restrict__ W,
    const float* __restrict__ mu, const float* __restrict__ logvar,
    const float* __restrict__ eps, const float* __restrict__ b,
    float* __restrict__ y, int CB, int convBase,
    const void* __restrict__ adj, u64* __restrict__ bm) {
  if (convFirst(CB, convBase, adj, bm)) return;
  __shared__ float zsh[512];
  for (int k = threadIdx.x; k < 512; k += 256)
    zsh[k] = mu[k] + eps[k] * expf(0.5f * logvar[k]);
  __syncthreads();
  const int r = blockIdx.x - CB;
  const float* row = W + (size_t)r * 512u;
  const int c = threadIdx.x * 2;
  const float2 w2 = *reinterpret_cast<const float2*>(row + c);
  float acc = w2.x * zsh[c] + w2.y * zsh[c + 1];
  acc = waveRed(acc);
  __shared__ float lds[4];
  if ((threadIdx.x & 63) == 0) lds[threadIdx.x >> 6] = acc;
  __syncthreads();
  if (threadIdx.x == 0) {
    float v = lds[0] + lds[1] + lds[2] + lds[3] + b[r];
    y[r] = v > 0.f ? v : 0.f;
  }
}

// 4 heads fused, bitmap scan. One wave per row; lane = bitmap word index.
__global__ __launch_bounds__(256) void gat_heads_bm(const u64* __restrict__ bm,
    const float* __restrict__ xh, const float* __restrict__ consts,
    float* __restrict__ wh2) {
  const int lane = threadIdx.x & 63;
  const int i = blockIdx.x * 4 + (threadIdx.x >> 6);
  const float xi = xh[i];
  const float A0 = consts[0] * xi, A1 = consts[1] * xi,
              A2 = consts[2] * xi, A3 = consts[3] * xi;
  const float c20 = consts[4], c21 = consts[5], c22 = consts[6], c23 = consts[7];
  float s0 = 0, s1 = 0, s2 = 0, s3 = 0, t0 = 0, t1 = 0, t2 = 0, t3 = 0;
  u64 m = bm[(size_t)i * 64 + lane];
  const int qbase = ((lane >> 2) << 8) | (lane & 3);
  while (m) {
    const int bp = __builtin_ctzll(m);
    m &= m - 1;
    const float xj = xh[qbase + (bp << 2)];
    float e0 = A0 + c20 * xj, e1 = A1 + c21 * xj, e2 = A2 + c22 * xj, e3 = A3 + c23 * xj;
    e0 = fmaxf(e0, 0.2f * e0); e1 = fmaxf(e1, 0.2f * e1);
    e2 = fmaxf(e2, 0.2f * e2); e3 = fmaxf(e3, 0.2f * e3);
    const float w0 = expf(e0), w1 = expf(e1), w2 = expf(e2), w3 = expf(e3);
    s0 += w0; s1 += w1; s2 += w2; s3 += w3;
    t0 += w0 * xj; t1 += w1 * xj; t2 += w2 * xj; t3 += w3 * xj;
  }
  for (int o = 1; o < 64; o <<= 1) {
    s0 += __shfl_xor(s0, o); s1 += __shfl_xor(s1, o);
    s2 += __shfl_xor(s2, o); s3 += __shfl_xor(s3, o);
    t0 += __shfl_xor(t0, o); t1 += __shfl_xor(t1, o);
    t2 += __shfl_xor(t2, o); t3 += __shfl_xor(t3, o);
  }
  float r0, r1, r2, r3;
  if (s0 != 0.f) { r0 = t0 / s0; r1 = t1 / s1; r2 = t2 / s2; r3 = t3 / s3; }
  else {  // empty row -> uniform attention (mean of xh)
    float a = 0.f;
    for (int k = lane; k < 4096; k += 64) a += xh[k];
    for (int o = 1; o < 64; o <<= 1) a += __shfl_xor(a, o);
    r0 = r1 = r2 = r3 = a * (1.f / 4096.f);
  }
  if (lane == 0)
    wh2[i] = consts[8] * r0 + consts[9] * r1 + consts[10] * r2 + consts[11] * r3;
}

// Output GAT layer (f=1), bitmap scan. y = elu(att @ Wh2).
__global__ __launch_bounds__(256) void gat_out_bm(const u64* __restrict__ bm,
    const float* __restrict__ wh2, const float* __restrict__ consts,
    float* __restrict__ yhat) {
  const int lane = threadIdx.x & 63;
  const int i = blockIdx.x * 4 + (threadIdx.x >> 6);
  const float Ai = consts[12] * wh2[i];
  const float oa1 = consts[13];
  float s = 0.f, t = 0.f;
  u64 m = bm[(size_t)i * 64 + lane];
  const int qbase = ((lane >> 2) << 8) | (lane & 3);
  while (m) {
    const int bp = __builtin_ctzll(m);
    m &= m - 1;
    const float wj = wh2[qbase + (bp << 2)];
    float e = Ai + oa1 * wj;
    e = fmaxf(e, 0.2f * e);
    const float ww = expf(e);
    s += ww; t += ww * wj;
  }
  for (int o = 1; o < 64; o <<= 1) {
    s += __shfl_xor(s, o);
    t += __shfl_xor(t, o);
  }
  float v;
  if (s != 0.f) v = t / s;
  else {
    float a = 0.f;
    for (int k = lane; k < 4096; k += 64) a += wh2[k];
    for (int o = 1; o < 64; o <<= 1) a += __shfl_xor(a, o);
    v = a * (1.f / 4096.f);
  }
  if (lane == 0) yhat[i] = v > 0.f ? v : expm1f(v);
}

extern "C" void kernel_launch(void* const* d_in, const int* in_sizes, int n_in,
                              void* d_out, int out_size, void* d_ws, size_t ws_size,
                              hipStream_t stream) {
  const float* x      = (const float*)d_in[0];
  const float* eps    = (const float*)d_in[1];
  const void*  adj    = d_in[2];
  const float* enc_w1 = (const float*)d_in[3];
  const float* enc_b1 = (const float*)d_in[4];
  const float* enc_w2 = (const float*)d_in[5];
  const float* enc_b2 = (const float*)d_in[6];
  const float* enc_w3 = (const float*)d_in[7];
  const float* enc_b3 = (const float*)d_in[8];
  const float* enc_w4 = (const float*)d_in[9];
  const float* enc_b4 = (const float*)d_in[10];
  const float* dec_w1 = (const float*)d_in[11];
  const float* dec_b1 = (const float*)d_in[12];
  const float* dec_w2 = (const float*)d_in[13];
  const float* dec_b2 = (const float*)d_in[14];
  const float* dec_w3 = (const float*)d_in[15];
  const float* dec_b3 = (const float*)d_in[16];
  const float* gat_W  = (const float*)d_in[17];
  const float* gat_a  = (const float*)d_in[18];
  const float* out_W  = (const float*)d_in[19];
  const float* out_a  = (const float*)d_in[20];

  float* out    = (float*)d_out;
  float* xhat   = out;          // [0,4096)
  float* yhat   = out + 4096;   // [4096,8192)
  float* mu     = out + 8192;   // [8192,8704)
  float* logvar = out + 8704;   // [8704,9216)

  const size_t BM_BYTES = (size_t)4096 * 64 * sizeof(u64);  // 2 MiB
  u64*   bm     = (u64*)d_ws;
  float* F      = (float*)((char*)d_ws + BM_BYTES);
  float* h1     = F;            // 1024
  float* h2     = F + 1024;     // 1024
  float* h3     = F + 2048;     // 1024
  float* h4     = F + 3072;     // 1024
  float* wh2    = F + 4096;     // 4096
  float* consts = F + 8208;     // 14

  // Tapered conv packing: rows [0,1792) mega, then 4x384, then 768 in dec3.
  // Dispatch 1: conv(448) + enc1(1024) + prep(1).
  MegaP mp;
  mp.adj = adj; mp.bm = bm;
  mp.w1 = enc_w1; mp.x = x; mp.b1 = enc_b1; mp.h1 = h1;
  mp.gw = gat_W; mp.ga = gat_a; mp.ow = out_W; mp.oa = out_a;
  mp.consts = consts;
  mega_kernel<<<1473, 256, 0, stream>>>(mp);

  // VAE chain, each with a conv slice at low blockIdx.
  mv_conv_kernel<ACT_RELU><<<96 + 1024, 256, 0, stream>>>(
      enc_w2, h1, enc_b2, h2, 1024, 96, 1792, adj, bm);
  mulv_conv_kernel<<<96 + 1024, 256, 0, stream>>>(
      enc_w3, enc_b3, enc_w4, enc_b4, h2, mu, logvar, 96, 2176, adj, bm);
  dec1_conv_kernel<<<96 + 1024, 256, 0, stream>>>(
      dec_w1, mu, logvar, eps, dec_b1, h3, 96, 2560, adj, bm);
  mv_conv_kernel<ACT_RELU><<<96 + 1024, 256, 0, stream>>>(
      dec_w2, h3, dec_b2, h4, 1024, 96, 2944, adj, bm);
  mv_conv_kernel<ACT_SIG><<<192 + 4096, 256, 0, stream>>>(
      dec_w3, h4, dec_b3, xhat, 1024, 192, 3328, adj, bm);

  // GAT (bitmap + consts complete by stream order).
  gat_heads_bm<<<1024, 256, 0, stream>>>(bm, xhat, consts, wh2);
  gat_out_bm<<<1024, 256, 0, stream>>>(bm, wh2, consts, yhat);
}

// Round 8
// 43.026 us; speedup vs baseline: 1.3999x; 1.3999x over previous
//
#include <hip/hip_runtime.h>
#include <cstdint>
#include <cstddef>

// ---------------------------------------------------------------------------
// DeepIM: VAE (matvec chain) + 2-layer GAT on 1%-dense adjacency.
//  - GAT heads are rank-1 => logits e[i,j]=leaky(c1*xh[i]+c2*xh[j]); head
//    outputs collapse to scalars. No NxN / Nx64 intermediates.
//  - adjacency (int32/float32 words; R1 counters ruled out packed bytes)
//    -> per-row CSR (u16 cols, ~41/row), scanned in ONE wave iteration.
//  - R8 structure = R6 skeleton (proven 44.3us): 8 dispatches, conv packed
//    wide (1024 blocks, FIRST) into the mega dispatch with enc1+prep.
//  - R3/R4 lesson: device-scope spin barriers cost ~70us each at 512 blocks —
//    never hand-roll grid sync; dispatch boundaries are ~1.2us.
//  - R5/R7 lesson (twice-burned): conv side-work below ~1024 blocks runs at
//    ~13GB/s/block and EXTENDS any short host stage; only the mega dispatch
//    can host conv. No tapering.
// ---------------------------------------------------------------------------

typedef unsigned long long u64;

#define ACT_RELU 1
#define ACT_SIG  2

__device__ __forceinline__ float d4(float4 a, float4 b) {
  return a.x * b.x + a.y * b.y + a.z * b.z + a.w * b.w;
}
__device__ __forceinline__ float waveRed(float v) {
  for (int o = 32; o; o >>= 1) v += __shfl_down(v, o);
  return v;  // lane 0 holds sum
}

// conv: one adjacency row (4096 int32 words, uint4 per lane) -> sorted CSR.
// Element e = it*64+lane covers cols 4e..4e+3, i.e. col = it*256+4*lane+c.
// Wave-uniform running count via ballot+popcount; per-lane offset via
// prefix popcount. Cap 1024 (row degree ~41±6; overflow impossible for
// binomial(4096,0.01) input — clamp guards OOB anyway).
__device__ __forceinline__ void csrRow(const uint4* aw, unsigned short* edges,
                                       unsigned* cnt, int r, int lane) {
  const uint4* rp = aw + (size_t)r * 1024u;
  unsigned short* er = edges + (size_t)r * 1024u;
  const u64 pm = (~0ull) >> (63 - lane);  // bits [0,lane] ; we want strictly below:
  const u64 pmb = pm >> 1;                // bits [0,lane)
  unsigned total = 0;
#pragma unroll
  for (int it = 0; it < 16; ++it) {
    const uint4 v = rp[it * 64 + lane];
    const int colb = it * 256 + 4 * lane;
    u64 m;
    m = __ballot(v.x != 0u);
    if (v.x) er[min(total + (unsigned)__popcll(m & pmb), 1023u)] = (unsigned short)colb;
    total += (unsigned)__popcll(m);
    m = __ballot(v.y != 0u);
    if (v.y) er[min(total + (unsigned)__popcll(m & pmb), 1023u)] = (unsigned short)(colb + 1);
    total += (unsigned)__popcll(m);
    m = __ballot(v.z != 0u);
    if (v.z) er[min(total + (unsigned)__popcll(m & pmb), 1023u)] = (unsigned short)(colb + 2);
    total += (unsigned)__popcll(m);
    m = __ballot(v.w != 0u);
    if (v.w) er[min(total + (unsigned)__popcll(m & pmb), 1023u)] = (unsigned short)(colb + 3);
    total += (unsigned)__popcll(m);
  }
  if (lane == 0) cnt[r] = min(total, 1024u);
}

// Mega dispatch #1: [0,1024) conv->CSR (4 rows/block, 1 row/wave);
// [1024,2048) enc1 rows; block 2048: GAT prep scalars. All independent.
struct MegaP {
  const void* adj;
  unsigned short* edges;
  unsigned* cnt;
  const float *w1, *x, *b1;
  float* h1;
  const float *gw, *ga, *ow, *oa;
  float* consts;  // [c1(4), c2(4), d(4), oa0, oa1]
};

__global__ __launch_bounds__(256) void mega_kernel(MegaP p) {
  const int tid = threadIdx.x, w = tid >> 6, lane = tid & 63;
  const int blk = blockIdx.x;
  if (blk < 1024) {                        // ---- conv rows blk*4+w
    csrRow((const uint4*)p.adj, p.edges, p.cnt, blk * 4 + w, lane);
    return;
  }
  if (blk < 2048) {                        // ---- enc1 row
    const int r = blk - 1024;
    const float4* row = (const float4*)(p.w1 + (size_t)r * 4096u);
    const float4* x4 = (const float4*)p.x;
    float acc = 0.f;
#pragma unroll
    for (int k = 0; k < 4; ++k) {
      const int idx = tid + 256 * k;
      acc += d4(row[idx], x4[idx]);
    }
    acc = waveRed(acc);
    __shared__ float lds[4];
    if (lane == 0) lds[w] = acc;
    __syncthreads();
    if (tid == 0) {
      const float v = lds[0] + lds[1] + lds[2] + lds[3] + p.b1[r];
      p.h1[r] = v > 0.f ? v : 0.f;
    }
    return;
  }
  // ---- prep: per-head scalars (1 block)
  const int h = w, k = lane;
  const float wv = p.gw[h * 64 + k];
  float p1 = wv * p.ga[h * 128 + k];
  float p2 = wv * p.ga[h * 128 + 64 + k];
  float p3 = wv * p.ow[h * 64 + k];
  for (int off = 32; off; off >>= 1) {
    p1 += __shfl_down(p1, off);
    p2 += __shfl_down(p2, off);
    p3 += __shfl_down(p3, off);
  }
  if (k == 0) { p.consts[h] = p1; p.consts[4 + h] = p2; p.consts[8 + h] = p3; }
  if (tid == 0) { p.consts[12] = p.oa[0]; p.consts[13] = p.oa[1]; }
}

// y[r] = act( dot(W[r,:], x) + b[r] );  one block (256 thr) per row.
template<int ACT>
__global__ __launch_bounds__(256) void mv_kernel(const float* __restrict__ W,
    const float* __restrict__ x, const float* __restrict__ b,
    float* __restrict__ y, int C) {
  const int r = blockIdx.x;
  const float* row = W + (size_t)r * (size_t)C;
  float acc = 0.f;
  for (int c = threadIdx.x * 4; c < C; c += 256 * 4) {
    const float4 w4 = *reinterpret_cast<const float4*>(row + c);
    const float4 x4 = *reinterpret_cast<const float4*>(x + c);
    acc += d4(w4, x4);
  }
  acc = waveRed(acc);
  __shared__ float lds[4];
  if ((threadIdx.x & 63) == 0) lds[threadIdx.x >> 6] = acc;
  __syncthreads();
  if (threadIdx.x == 0) {
    float v = lds[0] + lds[1] + lds[2] + lds[3] + b[r];
    if (ACT == ACT_RELU) v = v > 0.f ? v : 0.f;
    if (ACT == ACT_SIG)  v = 1.f / (1.f + expf(-v));
    y[r] = v;
  }
}

// mu (rows 0..511 via w3) and logvar (rows 512..1023 via w4) in one grid.
__global__ __launch_bounds__(256) void mulv_kernel(const float* __restrict__ w3,
    const float* __restrict__ b3, const float* __restrict__ w4,
    const float* __restrict__ b4, const float* __restrict__ h2,
    float* __restrict__ mu, float* __restrict__ logvar) {
  const int r = blockIdx.x;
  const bool is_mu = r < 512;
  const int rr = is_mu ? r : r - 512;
  const float* row = (is_mu ? w3 : w4) + (size_t)rr * 1024u;
  const int c = threadIdx.x * 4;
  float acc = d4(*reinterpret_cast<const float4*>(row + c),
                 *reinterpret_cast<const float4*>(h2 + c));
  acc = waveRed(acc);
  __shared__ float lds[4];
  if ((threadIdx.x & 63) == 0) lds[threadIdx.x >> 6] = acc;
  __syncthreads();
  if (threadIdx.x == 0) {
    const float v = lds[0] + lds[1] + lds[2] + lds[3] + (is_mu ? b3[rr] : b4[rr]);
    (is_mu ? mu : logvar)[rr] = v;
  }
}

// dec1 with z = mu + eps*exp(0.5*logvar) computed in LDS per block.
__global__ __launch_bounds__(256) void dec1_kernel(const float* __restrict__ W,
    const float* __restrict__ mu, const float* __restrict__ logvar,
    const float* __restrict__ eps, const float* __restrict__ b,
    float* __restrict__ y) {
  __shared__ float zsh[512];
  for (int k = threadIdx.x; k < 512; k += 256)
    zsh[k] = mu[k] + eps[k] * expf(0.5f * logvar[k]);
  __syncthreads();
  const int r = blockIdx.x;
  const float* row = W + (size_t)r * 512u;
  const int c = threadIdx.x * 2;
  const float2 w2 = *reinterpret_cast<const float2*>(row + c);
  float acc = w2.x * zsh[c] + w2.y * zsh[c + 1];
  acc = waveRed(acc);
  __shared__ float lds[4];
  if ((threadIdx.x & 63) == 0) lds[threadIdx.x >> 6] = acc;
  __syncthreads();
  if (threadIdx.x == 0) {
    float v = lds[0] + lds[1] + lds[2] + lds[3] + b[r];
    y[r] = v > 0.f ? v : 0.f;
  }
}

// 4 heads fused, CSR scan. One wave per row; lane j handles edge j
// (typical degree ~41 < 64 -> single iteration).
__global__ __launch_bounds__(256) void gat_heads_csr(
    const unsigned short* __restrict__ edges, const unsigned* __restrict__ cnt,
    const float* __restrict__ xh, const float* __restrict__ consts,
    float* __restrict__ wh2) {
  const int lane = threadIdx.x & 63;
  const int i = blockIdx.x * 4 + (threadIdx.x >> 6);
  const unsigned n = cnt[i];
  const float xi = xh[i];
  const float A0 = consts[0] * xi, A1 = consts[1] * xi,
              A2 = consts[2] * xi, A3 = consts[3] * xi;
  const float c20 = consts[4], c21 = consts[5], c22 = consts[6], c23 = consts[7];
  float s0 = 0, s1 = 0, s2 = 0, s3 = 0, t0 = 0, t1 = 0, t2 = 0, t3 = 0;
  const unsigned short* er = edges + (size_t)i * 1024u;
  for (unsigned j = lane; j < n; j += 64) {
    const float xj = xh[er[j]];
    float e0 = A0 + c20 * xj, e1 = A1 + c21 * xj, e2 = A2 + c22 * xj, e3 = A3 + c23 * xj;
    e0 = fmaxf(e0, 0.2f * e0); e1 = fmaxf(e1, 0.2f * e1);
    e2 = fmaxf(e2, 0.2f * e2); e3 = fmaxf(e3, 0.2f * e3);
    const float w0 = expf(e0), w1 = expf(e1), w2 = expf(e2), w3 = expf(e3);
    s0 += w0; s1 += w1; s2 += w2; s3 += w3;
    t0 += w0 * xj; t1 += w1 * xj; t2 += w2 * xj; t3 += w3 * xj;
  }
  for (int o = 1; o < 64; o <<= 1) {
    s0 += __shfl_xor(s0, o); s1 += __shfl_xor(s1, o);
    s2 += __shfl_xor(s2, o); s3 += __shfl_xor(s3, o);
    t0 += __shfl_xor(t0, o); t1 += __shfl_xor(t1, o);
    t2 += __shfl_xor(t2, o); t3 += __shfl_xor(t3, o);
  }
  float r0, r1, r2, r3;
  if (n != 0) { r0 = t0 / s0; r1 = t1 / s1; r2 = t2 / s2; r3 = t3 / s3; }
  else {  // empty row -> uniform attention (mean of xh)
    float a = 0.f;
    for (int k = lane; k < 4096; k += 64) a += xh[k];
    for (int o = 1; o < 64; o <<= 1) a += __shfl_xor(a, o);
    r0 = r1 = r2 = r3 = a * (1.f / 4096.f);
  }
  if (lane == 0)
    wh2[i] = consts[8] * r0 + consts[9] * r1 + consts[10] * r2 + consts[11] * r3;
}

// Output GAT layer (f=1), CSR scan. y = elu(att @ Wh2).
__global__ __launch_bounds__(256) void gat_out_csr(
    const unsigned short* __restrict__ edges, const unsigned* __restrict__ cnt,
    const float* __restrict__ wh2, const float* __restrict__ consts,
    float* __restrict__ yhat) {
  const int lane = threadIdx.x & 63;
  const int i = blockIdx.x * 4 + (threadIdx.x >> 6);
  const unsigned n = cnt[i];
  const float Ai = consts[12] * wh2[i];
  const float oa1 = consts[13];
  float s = 0.f, t = 0.f;
  const unsigned short* er = edges + (size_t)i * 1024u;
  for (unsigned j = lane; j < n; j += 64) {
    const float wj = wh2[er[j]];
    float e = Ai + oa1 * wj;
    e = fmaxf(e, 0.2f * e);
    const float ww = expf(e);
    s += ww; t += ww * wj;
  }
  for (int o = 1; o < 64; o <<= 1) {
    s += __shfl_xor(s, o);
    t += __shfl_xor(t, o);
  }
  float v;
  if (n != 0) v = t / s;
  else {
    float a = 0.f;
    for (int k = lane; k < 4096; k += 64) a += wh2[k];
    for (int o = 1; o < 64; o <<= 1) a += __shfl_xor(a, o);
    v = a * (1.f / 4096.f);
  }
  if (lane == 0) yhat[i] = v > 0.f ? v : expm1f(v);
}

extern "C" void kernel_launch(void* const* d_in, const int* in_sizes, int n_in,
                              void* d_out, int out_size, void* d_ws, size_t ws_size,
                              hipStream_t stream) {
  const float* x      = (const float*)d_in[0];
  const float* eps    = (const float*)d_in[1];
  const void*  adj    = d_in[2];
  const float* enc_w1 = (const float*)d_in[3];
  const float* enc_b1 = (const float*)d_in[4];
  const float* enc_w2 = (const float*)d_in[5];
  const float* enc_b2 = (const float*)d_in[6];
  const float* enc_w3 = (const float*)d_in[7];
  const float* enc_b3 = (const float*)d_in[8];
  const float* enc_w4 = (const float*)d_in[9];
  const float* enc_b4 = (const float*)d_in[10];
  const float* dec_w1 = (const float*)d_in[11];
  const float* dec_b1 = (const float*)d_in[12];
  const float* dec_w2 = (const float*)d_in[13];
  const float* dec_b2 = (const float*)d_in[14];
  const float* dec_w3 = (const float*)d_in[15];
  const float* dec_b3 = (const float*)d_in[16];
  const float* gat_W  = (const float*)d_in[17];
  const float* gat_a  = (const float*)d_in[18];
  const float* out_W  = (const float*)d_in[19];
  const float* out_a  = (const float*)d_in[20];

  float* out    = (float*)d_out;
  float* xhat   = out;          // [0,4096)
  float* yhat   = out + 4096;   // [4096,8192)
  float* mu     = out + 8192;   // [8192,8704)
  float* logvar = out + 8704;   // [8704,9216)

  // ws layout: edges 8MB | cnt 16KB | float scratch
  unsigned short* edges = (unsigned short*)d_ws;
  unsigned* cnt = (unsigned*)((char*)d_ws + (size_t)4096 * 1024 * 2);
  float* F      = (float*)((char*)cnt + 4096 * sizeof(unsigned));
  float* h1     = F;            // 1024
  float* h2     = F + 1024;     // 1024
  float* h3     = F + 2048;     // 1024
  float* h4     = F + 3072;     // 1024
  float* wh2    = F + 4096;     // 4096
  float* consts = F + 8208;     // 14

  // Dispatch 1: conv->CSR (1024 blocks) + enc1 (1024 blocks) + prep (1).
  MegaP mp;
  mp.adj = adj; mp.edges = edges; mp.cnt = cnt;
  mp.w1 = enc_w1; mp.x = x; mp.b1 = enc_b1; mp.h1 = h1;
  mp.gw = gat_W; mp.ga = gat_a; mp.ow = out_W; mp.oa = out_a;
  mp.consts = consts;
  mega_kernel<<<2049, 256, 0, stream>>>(mp);

  // VAE chain (each stage depends fully on the previous).
  mv_kernel<ACT_RELU><<<1024, 256, 0, stream>>>(enc_w2, h1, enc_b2, h2, 1024);
  mulv_kernel<<<1024, 256, 0, stream>>>(enc_w3, enc_b3, enc_w4, enc_b4, h2, mu, logvar);
  dec1_kernel<<<1024, 256, 0, stream>>>(dec_w1, mu, logvar, eps, dec_b1, h3);
  mv_kernel<ACT_RELU><<<1024, 256, 0, stream>>>(dec_w2, h3, dec_b2, h4, 1024);
  mv_kernel<ACT_SIG ><<<4096, 256, 0, stream>>>(dec_w3, h4, dec_b3, xhat, 1024);

  // GAT (CSR + consts ready since dispatch 1, by stream order).
  gat_heads_csr<<<1024, 256, 0, stream>>>(edges, cnt, xhat, consts, wh2);
  gat_out_csr<<<1024, 256, 0, stream>>>(edges, cnt, wh2, consts, yhat);
}